// Round 2
// 605.670 us; speedup vs baseline: 1.0018x; 1.0018x over previous
//
#include <hip/hip_runtime.h>

// Nearest-neighbor 2x upsample, NHWC fp32.
// x: (B=8, H=128, W=128, C=256) -> out: (8, 256, 256, 256)
// One 64-lane wave per input pixel. lane = c4 (C/4 = 64 float4 per pixel).
// 16B/lane coalesced load; 4 contiguous 1 KiB wave-level stores.
// Non-temporal load/store via clang native vector type (HIP float4 is a
// class and is rejected by __builtin_nontemporal_*).

#define B_  8
#define H_  128
#define W_  128
#define C4_ 64    // 256 channels / 4 floats per float4

typedef float v4f __attribute__((ext_vector_type(4)));

__global__ __launch_bounds__(256)
void Projector2D_34720515620931_kernel(const v4f* __restrict__ in,
                                       v4f* __restrict__ out) {
    const int gid  = blockIdx.x * blockDim.x + threadIdx.x;
    const int pix  = gid >> 6;   // global wave id == input pixel id
    const int lane = gid & 63;   // c4 index

    // pix -> (b, h, w), W=128, H=128 (powers of two)
    const int w  = pix & (W_ - 1);
    const int hb = pix >> 7;
    const int h  = hb & (H_ - 1);
    const int b  = hb >> 7;

    const v4f v = __builtin_nontemporal_load(&in[(size_t)pix * C4_ + lane]);

    // output: (b, 2h+dh, 2w+dw, c4) with H2=W2=256
    const size_t row   = (size_t)256 * C4_;                       // one output row of float4
    const size_t base  = (((size_t)b * 256 + 2 * h) * 256 + 2 * w) * C4_ + lane;

    __builtin_nontemporal_store(v, &out[base]);             // (2h,   2w)
    __builtin_nontemporal_store(v, &out[base + C4_]);       // (2h,   2w+1)
    __builtin_nontemporal_store(v, &out[base + row]);       // (2h+1, 2w)
    __builtin_nontemporal_store(v, &out[base + row + C4_]); // (2h+1, 2w+1)
}

extern "C" void kernel_launch(void* const* d_in, const int* in_sizes, int n_in,
                              void* d_out, int out_size, void* d_ws, size_t ws_size,
                              hipStream_t stream) {
    const v4f* in  = (const v4f*)d_in[0];
    v4f*       out = (v4f*)d_out;

    const int n_pix    = B_ * H_ * W_;       // 131072 input pixels
    const int n_thread = n_pix * 64;         // one wave per pixel
    const int block    = 256;
    const int grid     = n_thread / block;   // 32768, exact

    Projector2D_34720515620931_kernel<<<grid, block, 0, stream>>>(in, out);
}

// Round 3
// 603.600 us; speedup vs baseline: 1.0053x; 1.0034x over previous
//
#include <hip/hip_runtime.h>

// Nearest-neighbor 2x upsample, NHWC fp32.
// x: (B=8, H=128, W=128, C=256) -> out: (8, 256, 256, 256)
//
// Streaming structure: fixed grid (2048 blocks x 256 thr = 8192 waves),
// each wave owns 16 CONSECUTIVE input pixels (one 16 KiB input chunk,
// two 32 KiB contiguous output row segments). Software-pipelined depth-2:
// next pixel's load is issued before current pixel's 4 stores, so the
// ~900-cycle HBM load latency hides under store issue instead of stalling
// 131072 one-shot waves (previous shape).
// lane = c4 (C/4 = 64 float4 per pixel); 16 B/lane, 1 KiB per wave access.

#define B_   8
#define H_   128
#define W_   128
#define C4_  64                 // 256 channels / 4 floats per float4
#define N_PIX  (B_ * H_ * W_)   // 131072
#define PPW    16               // pixels per wave (chunk stays inside one row: 16 | 128)
#define BLOCK  256
#define NWAVES (N_PIX / PPW)    // 8192
#define GRID   (NWAVES * 64 / BLOCK)  // 2048

typedef float v4f __attribute__((ext_vector_type(4)));

__global__ __launch_bounds__(BLOCK)
void Projector2D_34720515620931_kernel(const v4f* __restrict__ in,
                                       v4f* __restrict__ out) {
    const int gid  = blockIdx.x * BLOCK + threadIdx.x;
    const int wv   = gid >> 6;
    const int lane = gid & 63;

    // chunk start pixel; pix0 is a multiple of 16, so the 16-pixel chunk
    // stays within one input row (W=128): b,h fixed, w = w0..w0+15.
    const int pix0 = wv * PPW;
    const int w0   = pix0 & (W_ - 1);
    const int hb   = pix0 >> 7;
    const int h    = hb & (H_ - 1);
    const int b    = hb >> 7;

    const size_t row = (size_t)(2 * W_) * C4_;   // one output row of float4 (256*64)
    const size_t ib  = (size_t)pix0 * C4_ + lane;
    const size_t ob  = (((size_t)b * (2 * H_) + 2 * h) * (2 * W_) + 2 * w0) * C4_ + lane;

    v4f v = __builtin_nontemporal_load(&in[ib]);
    #pragma unroll
    for (int i = 0; i < PPW - 1; ++i) {
        // prefetch next pixel before draining current stores
        v4f vn = __builtin_nontemporal_load(&in[ib + (size_t)(i + 1) * C4_]);
        const size_t o = ob + (size_t)i * (2 * C4_);
        __builtin_nontemporal_store(v, &out[o]);              // (2h,   2w)
        __builtin_nontemporal_store(v, &out[o + C4_]);        // (2h,   2w+1)
        __builtin_nontemporal_store(v, &out[o + row]);        // (2h+1, 2w)
        __builtin_nontemporal_store(v, &out[o + row + C4_]);  // (2h+1, 2w+1)
        v = vn;
    }
    const size_t o = ob + (size_t)(PPW - 1) * (2 * C4_);
    __builtin_nontemporal_store(v, &out[o]);
    __builtin_nontemporal_store(v, &out[o + C4_]);
    __builtin_nontemporal_store(v, &out[o + row]);
    __builtin_nontemporal_store(v, &out[o + row + C4_]);
}

extern "C" void kernel_launch(void* const* d_in, const int* in_sizes, int n_in,
                              void* d_out, int out_size, void* d_ws, size_t ws_size,
                              hipStream_t stream) {
    const v4f* in  = (const v4f*)d_in[0];
    v4f*       out = (v4f*)d_out;

    Projector2D_34720515620931_kernel<<<GRID, BLOCK, 0, stream>>>(in, out);
}